// Round 3
// baseline (206.750 us; speedup 1.0000x reference)
//
#include <hip/hip_runtime.h>

#define NDIM 16
#define HID  64
#define G3   192   // 3*HID
#define NCLS 2
#define BB   16
#define TT   64
#define NN   400
#define NQ   4        // row-quarters per tile
#define QROWS (NN / NQ)   // 100

// ws layout: [0, 6.55MB) partial colsums; [8MB, 8MB+768KB) gi
#define GI_OFS (8u << 20)

// ---------------------------------------------------------------------------
// Kernel A: pure streaming partial column-sums.
// block g = (tile bt, quarter q). 128 threads, 100 active float4-columns.
// No LDS, no barriers, ~56 VGPRs -> full occupancy, copy-like.
// ---------------------------------------------------------------------------
__global__ __launch_bounds__(128) void colsum_kernel(
    const float* __restrict__ adj_seq,
    float4* __restrict__ part4)
{
    const int g  = blockIdx.x;            // 0 .. BB*TT*NQ-1
    const int bt = g >> 2;
    const int q  = g & 3;
    const int t  = threadIdx.x;
    if (t >= 100) return;

    const float* __restrict__ base =
        adj_seq + (size_t)bt * NN * NN + (size_t)q * QROWS * NN + t * 4;

    float4 cs = make_float4(0.f, 0.f, 0.f, 0.f);
    #pragma unroll 10
    for (int i = 0; i < QROWS; i++) {
        float4 v = *reinterpret_cast<const float4*>(base + (size_t)i * NN);
        cs.x += v.x; cs.y += v.y; cs.z += v.z; cs.w += v.w;
    }
    part4[(size_t)g * 100 + t] = cs;
}

// ---------------------------------------------------------------------------
// Kernel B: per-tile: combine partials -> colsum, y = colsum@x (+sum),
// feats = (y@Wp + s*bp)/N, gi = b_ih + feats@W_ih^T -> ws.
// ---------------------------------------------------------------------------
__global__ __launch_bounds__(256) void tile_kernel(
    const float* __restrict__ x_seq,
    const float4* __restrict__ part4,
    const float* __restrict__ Wp,
    const float* __restrict__ bp,
    const float* __restrict__ W_ih,
    const float* __restrict__ b_ih,
    float* __restrict__ gi_out)
{
    const int bt = blockIdx.x;
    const int tid = threadIdx.x;
    const float* __restrict__ xbt = x_seq + (size_t)bt * NN * NDIM;

    __shared__ __align__(16) float colsum[NN];
    __shared__ float wred[4][17];
    __shared__ float yf[17];
    __shared__ float ffin[HID];

    if (tid < 100) {
        const float4* p = part4 + (size_t)bt * NQ * 100 + tid;
        float4 a = p[0], b = p[100], c = p[200], d = p[300];
        float4 s;
        s.x = (a.x + b.x) + (c.x + d.x);
        s.y = (a.y + b.y) + (c.y + d.y);
        s.z = (a.z + b.z) + (c.z + d.z);
        s.w = (a.w + b.w) + (c.w + d.w);
        reinterpret_cast<float4*>(colsum)[tid] = s;
    }
    __syncthreads();

    // y[0:16] = colsum @ x ; y[16] = sum(colsum)
    float y[17];
    #pragma unroll
    for (int i = 0; i < 17; i++) y[i] = 0.f;
    #pragma unroll
    for (int r = 0; r < 2; r++) {
        const int m = tid + r * 256;
        if (m < NN) {
            float c = colsum[m];
            y[16] += c;
            const float4* xp = reinterpret_cast<const float4*>(xbt + m * NDIM);
            float4 v0 = xp[0], v1 = xp[1], v2 = xp[2], v3 = xp[3];
            y[0]  += c * v0.x;  y[1]  += c * v0.y;  y[2]  += c * v0.z;  y[3]  += c * v0.w;
            y[4]  += c * v1.x;  y[5]  += c * v1.y;  y[6]  += c * v1.z;  y[7]  += c * v1.w;
            y[8]  += c * v2.x;  y[9]  += c * v2.y;  y[10] += c * v2.z;  y[11] += c * v2.w;
            y[12] += c * v3.x;  y[13] += c * v3.y;  y[14] += c * v3.z;  y[15] += c * v3.w;
        }
    }
    #pragma unroll
    for (int off = 32; off >= 1; off >>= 1) {
        #pragma unroll
        for (int i = 0; i < 17; i++) y[i] += __shfl_down(y[i], off, 64);
    }
    const int lane = tid & 63;
    const int wv   = tid >> 6;   // 0..3
    if (lane == 0) {
        #pragma unroll
        for (int i = 0; i < 17; i++) wred[wv][i] = y[i];
    }
    __syncthreads();
    if (tid < 17) {
        yf[tid] = (wred[0][tid] + wred[1][tid]) + (wred[2][tid] + wred[3][tid]);
    }
    __syncthreads();

    if (tid < HID) {
        float acc = 0.f;
        #pragma unroll
        for (int d = 0; d < NDIM; d++) acc += yf[d] * Wp[d * HID + tid];
        ffin[tid] = (acc + yf[16] * bp[tid]) * (1.0f / (float)NN);
    }
    __syncthreads();

    if (tid < G3) {
        const float4* wr = reinterpret_cast<const float4*>(W_ih + tid * HID);
        float acc = b_ih[tid];
        #pragma unroll
        for (int k4 = 0; k4 < HID / 4; k4++) {
            float4 w = wr[k4];
            acc += ffin[4 * k4 + 0] * w.x + ffin[4 * k4 + 1] * w.y
                 + ffin[4 * k4 + 2] * w.z + ffin[4 * k4 + 3] * w.w;
        }
        gi_out[(size_t)bt * G3 + tid] = acc;
    }
}

// ---------------------------------------------------------------------------
// Kernel C: GRU, one wave (64 threads) per batch element. No inter-wave sync.
// Thread j owns h[j] and gate rows j, j+64, j+128 of W_hh (192 regs).
// ---------------------------------------------------------------------------
__global__ __launch_bounds__(64, 1) void gru_kernel(
    const float* __restrict__ gi_all,
    const float* __restrict__ W_hh,
    const float* __restrict__ b_hh,
    const float* __restrict__ Wc,
    const float* __restrict__ bc,
    float* __restrict__ out)
{
    const int b = blockIdx.x;
    const int j = threadIdx.x;   // 0..63

    float wr_[HID], wz_[HID], wn_[HID];
    #pragma unroll
    for (int k4 = 0; k4 < HID / 4; k4++) {
        float4 a = *reinterpret_cast<const float4*>(W_hh + (j)       * HID + 4 * k4);
        float4 c = *reinterpret_cast<const float4*>(W_hh + (j + 64)  * HID + 4 * k4);
        float4 d = *reinterpret_cast<const float4*>(W_hh + (j + 128) * HID + 4 * k4);
        wr_[4*k4+0]=a.x; wr_[4*k4+1]=a.y; wr_[4*k4+2]=a.z; wr_[4*k4+3]=a.w;
        wz_[4*k4+0]=c.x; wz_[4*k4+1]=c.y; wz_[4*k4+2]=c.z; wz_[4*k4+3]=c.w;
        wn_[4*k4+0]=d.x; wn_[4*k4+1]=d.y; wn_[4*k4+2]=d.z; wn_[4*k4+3]=d.w;
    }
    const float bhr = b_hh[j], bhz = b_hh[j + 64], bhn = b_hh[j + 128];

    __shared__ __align__(16) float hls[HID];
    float h = 0.f;

    const float* __restrict__ gi = gi_all + (size_t)b * TT * G3;
    float gr = gi[j], gz = gi[j + 64], gn = gi[j + 128];

    for (int t = 0; t < TT; t++) {
        hls[j] = h;
        __syncthreads();   // single wave: cheap; orders LDS write->reads

        // prefetch next step's gi
        float gr2 = 0.f, gz2 = 0.f, gn2 = 0.f;
        if (t + 1 < TT) {
            const float* gnx = gi + (t + 1) * G3;
            gr2 = gnx[j]; gz2 = gnx[j + 64]; gn2 = gnx[j + 128];
        }

        float ar0 = bhr, ar1 = 0.f, az0 = bhz, az1 = 0.f, an0 = bhn, an1 = 0.f;
        #pragma unroll
        for (int k4 = 0; k4 < HID / 4; k4++) {
            float4 hv = reinterpret_cast<const float4*>(hls)[k4];
            if (k4 & 1) {
                ar1 += hv.x*wr_[4*k4+0] + hv.y*wr_[4*k4+1] + hv.z*wr_[4*k4+2] + hv.w*wr_[4*k4+3];
                az1 += hv.x*wz_[4*k4+0] + hv.y*wz_[4*k4+1] + hv.z*wz_[4*k4+2] + hv.w*wz_[4*k4+3];
                an1 += hv.x*wn_[4*k4+0] + hv.y*wn_[4*k4+1] + hv.z*wn_[4*k4+2] + hv.w*wn_[4*k4+3];
            } else {
                ar0 += hv.x*wr_[4*k4+0] + hv.y*wr_[4*k4+1] + hv.z*wr_[4*k4+2] + hv.w*wr_[4*k4+3];
                az0 += hv.x*wz_[4*k4+0] + hv.y*wz_[4*k4+1] + hv.z*wz_[4*k4+2] + hv.w*wz_[4*k4+3];
                an0 += hv.x*wn_[4*k4+0] + hv.y*wn_[4*k4+1] + hv.z*wn_[4*k4+2] + hv.w*wn_[4*k4+3];
            }
        }
        float ghr = ar0 + ar1, ghz = az0 + az1, ghn = an0 + an1;

        float r  = 1.f / (1.f + expf(-(gr + ghr)));
        float z  = 1.f / (1.f + expf(-(gz + ghz)));
        float nv = tanhf(gn + r * ghn);
        h = (1.f - z) * nv + z * h;
        __syncthreads();   // all lanes done reading hls before next write

        gr = gr2; gz = gz2; gn = gn2;
    }

    // classifier: out[b,c] = bc[c] + sum_h h[h]*Wc[h,c]
    float c0 = h * Wc[j * NCLS + 0];
    float c1 = h * Wc[j * NCLS + 1];
    #pragma unroll
    for (int off = 32; off >= 1; off >>= 1) {
        c0 += __shfl_down(c0, off, 64);
        c1 += __shfl_down(c1, off, 64);
    }
    if (j == 0) {
        out[b * NCLS + 0] = c0 + bc[0];
        out[b * NCLS + 1] = c1 + bc[1];
    }
}

// ---------------------------------------------------------------------------
extern "C" void kernel_launch(void* const* d_in, const int* in_sizes, int n_in,
                              void* d_out, int out_size, void* d_ws, size_t ws_size,
                              hipStream_t stream) {
    const float* x_seq   = (const float*)d_in[0];
    const float* adj_seq = (const float*)d_in[1];
    const float* Wp      = (const float*)d_in[2];
    const float* bp      = (const float*)d_in[3];
    const float* W_ih    = (const float*)d_in[4];
    const float* W_hh    = (const float*)d_in[5];
    const float* b_ih    = (const float*)d_in[6];
    const float* b_hh    = (const float*)d_in[7];
    const float* Wc      = (const float*)d_in[8];
    const float* bc      = (const float*)d_in[9];

    float4* part4 = (float4*)d_ws;
    float*  gi    = (float*)((char*)d_ws + GI_OFS);
    float*  outp  = (float*)d_out;

    colsum_kernel<<<BB * TT * NQ, 128, 0, stream>>>(adj_seq, part4);
    tile_kernel<<<BB * TT, 256, 0, stream>>>(x_seq, part4, Wp, bp, W_ih, b_ih, gi);
    gru_kernel<<<BB, 64, 0, stream>>>(gi, W_hh, b_hh, Wc, bc, outp);
}

// Round 4
// 147.868 us; speedup vs baseline: 1.3982x; 1.3982x over previous
//
#include <hip/hip_runtime.h>

#define NDIM 16
#define HID  64
#define G3   192   // 3*HID
#define NCLS 2
#define BB   16
#define TT   64
#define NN   400

typedef float v4f __attribute__((ext_vector_type(4)));

// ---------------------------------------------------------------------------
// Kernel 1: per-(b,t) block (512 threads):
//   Phase A: colsum via perfectly-linear tile walk (500 threads x 80 steps,
//            stride 500 float4 -> block front is sequential 8KB chunks,
//            column-group per thread is constant: tid%100)
//   Phase B: y[d] = sum_m colsum[m]*x[m,d], y[16] = sum(colsum)
//   Phase C: feats = (y@Wp + y16*bp)/N   (LDS only)
//   Phase D: gi = b_ih + feats@W_ih^T -> ws
// ---------------------------------------------------------------------------
__global__ __launch_bounds__(512, 6) void feats_gi_kernel(
    const float* __restrict__ x_seq,
    const float* __restrict__ adj_seq,
    const float* __restrict__ Wp,
    const float* __restrict__ bp,
    const float* __restrict__ W_ih,
    const float* __restrict__ b_ih,
    float* __restrict__ gi_out)
{
    const int bt  = blockIdx.x;
    const int tid = threadIdx.x;
    const float* __restrict__ xbt = x_seq + (size_t)bt * NN * NDIM;

    __shared__ v4f   cpart[5][100];
    __shared__ __align__(16) float colsum[NN];
    __shared__ float wred[8][17];
    __shared__ float yf[17];
    __shared__ float ffin[HID];

    // ---- Phase A ----
    if (tid < 500) {
        const v4f* __restrict__ base =
            reinterpret_cast<const v4f*>(adj_seq + (size_t)bt * NN * NN) + tid;
        v4f cs = (v4f)(0.f);
        #pragma unroll 10
        for (int k = 0; k < 80; k++) {
            v4f v = __builtin_nontemporal_load(base + 500 * k);
            cs += v;
        }
        cpart[tid / 100][tid % 100] = cs;
    }
    __syncthreads();
    if (tid < 100) {
        v4f s = ((cpart[0][tid] + cpart[1][tid]) +
                 (cpart[2][tid] + cpart[3][tid])) + cpart[4][tid];
        *reinterpret_cast<v4f*>(colsum + 4 * tid) = s;
    }
    __syncthreads();

    // ---- Phase B: 400 threads, one m each ----
    float y[17];
    #pragma unroll
    for (int i = 0; i < 17; i++) y[i] = 0.f;
    if (tid < NN) {
        const int m = tid;
        float c = colsum[m];
        y[16] = c;
        const float4* xp = reinterpret_cast<const float4*>(xbt + m * NDIM);
        float4 v0 = xp[0], v1 = xp[1], v2 = xp[2], v3 = xp[3];
        y[0]  = c * v0.x;  y[1]  = c * v0.y;  y[2]  = c * v0.z;  y[3]  = c * v0.w;
        y[4]  = c * v1.x;  y[5]  = c * v1.y;  y[6]  = c * v1.z;  y[7]  = c * v1.w;
        y[8]  = c * v2.x;  y[9]  = c * v2.y;  y[10] = c * v2.z;  y[11] = c * v2.w;
        y[12] = c * v3.x;  y[13] = c * v3.y;  y[14] = c * v3.z;  y[15] = c * v3.w;
    }
    #pragma unroll
    for (int off = 32; off >= 1; off >>= 1) {
        #pragma unroll
        for (int i = 0; i < 17; i++) y[i] += __shfl_down(y[i], off, 64);
    }
    const int lane = tid & 63;
    const int wv   = tid >> 6;   // 0..7
    if (lane == 0) {
        #pragma unroll
        for (int i = 0; i < 17; i++) wred[wv][i] = y[i];
    }
    __syncthreads();
    if (tid < 17) {
        float s = 0.f;
        #pragma unroll
        for (int w = 0; w < 8; w++) s += wred[w][tid];
        yf[tid] = s;
    }
    __syncthreads();

    // ---- Phase C ----
    if (tid < HID) {
        float acc = 0.f;
        #pragma unroll
        for (int d = 0; d < NDIM; d++) acc += yf[d] * Wp[d * HID + tid];
        ffin[tid] = (acc + yf[16] * bp[tid]) * (1.0f / (float)NN);
    }
    __syncthreads();

    // ---- Phase D ----
    if (tid < G3) {
        const float4* wr = reinterpret_cast<const float4*>(W_ih + tid * HID);
        float acc = b_ih[tid];
        #pragma unroll
        for (int k4 = 0; k4 < HID / 4; k4++) {
            float4 w = wr[k4];
            acc += ffin[4 * k4 + 0] * w.x + ffin[4 * k4 + 1] * w.y
                 + ffin[4 * k4 + 2] * w.z + ffin[4 * k4 + 3] * w.w;
        }
        gi_out[(size_t)bt * G3 + tid] = acc;
    }
}

// ---------------------------------------------------------------------------
// Kernel 2: GRU recurrence (gh only; gi precomputed) + classifier.
// One block / batch element, 192 threads (3 waves), W_hh row in registers.
// ---------------------------------------------------------------------------
__device__ __forceinline__ float fast_sigmoid(float x) {
    x = fminf(fmaxf(x, -20.f), 20.f);
    return __builtin_amdgcn_rcpf(1.f + __expf(-x));
}
__device__ __forceinline__ float fast_tanh(float x) {
    x = fminf(fmaxf(x, -10.f), 10.f);
    float e2 = __expf(2.f * x);
    return (e2 - 1.f) * __builtin_amdgcn_rcpf(e2 + 1.f);
}

__global__ __launch_bounds__(192) void gru_kernel(
    const float* __restrict__ gi_all,
    const float* __restrict__ W_hh,
    const float* __restrict__ b_hh,
    const float* __restrict__ Wc,
    const float* __restrict__ bc,
    float* __restrict__ out)
{
    const int b = blockIdx.x;
    const int j = threadIdx.x;   // 0..191: wave0=r rows, wave1=z, wave2=n

    float whh[HID];
    #pragma unroll
    for (int k4 = 0; k4 < HID / 4; k4++) {
        float4 w = *reinterpret_cast<const float4*>(W_hh + j * HID + 4 * k4);
        whh[4 * k4 + 0] = w.x; whh[4 * k4 + 1] = w.y;
        whh[4 * k4 + 2] = w.z; whh[4 * k4 + 3] = w.w;
    }
    const float bh = b_hh[j];

    __shared__ __align__(16) float hst[HID];
    __shared__ float rbuf[HID], zbuf[HID], inb[HID], hnb[HID];
    float hreg = 0.f;
    if (j < HID) hst[j] = 0.f;
    __syncthreads();

    const float* __restrict__ gi = gi_all + (size_t)b * TT * G3;
    float gcur = gi[j];

    for (int t = 0; t < TT; t++) {
        float gnext = (t + 1 < TT) ? gi[(t + 1) * G3 + j] : 0.f;

        // gh = W_hh[j,:] @ h  with 4 independent partial chains
        float a0 = 0.f, a1 = 0.f, a2 = 0.f, a3 = 0.f;
        #pragma unroll
        for (int k4 = 0; k4 < HID / 4; k4 += 4) {
            float4 h0 = *reinterpret_cast<const float4*>(hst + 4 * (k4 + 0));
            float4 h1 = *reinterpret_cast<const float4*>(hst + 4 * (k4 + 1));
            float4 h2 = *reinterpret_cast<const float4*>(hst + 4 * (k4 + 2));
            float4 h3 = *reinterpret_cast<const float4*>(hst + 4 * (k4 + 3));
            a0 += h0.x*whh[4*k4+0]  + h0.y*whh[4*k4+1]  + h0.z*whh[4*k4+2]  + h0.w*whh[4*k4+3];
            a1 += h1.x*whh[4*k4+4]  + h1.y*whh[4*k4+5]  + h1.z*whh[4*k4+6]  + h1.w*whh[4*k4+7];
            a2 += h2.x*whh[4*k4+8]  + h2.y*whh[4*k4+9]  + h2.z*whh[4*k4+10] + h2.w*whh[4*k4+11];
            a3 += h3.x*whh[4*k4+12] + h3.y*whh[4*k4+13] + h3.z*whh[4*k4+14] + h3.w*whh[4*k4+15];
        }
        float gh = ((a0 + a1) + (a2 + a3)) + bh;

        if (j < 64) {
            rbuf[j] = fast_sigmoid(gcur + gh);
        } else if (j < 128) {
            zbuf[j - 64] = fast_sigmoid(gcur + gh);
        } else {
            inb[j - 128] = gcur;   // i_n
            hnb[j - 128] = gh;     // h_n
        }
        __syncthreads();

        if (j < HID) {
            float nv = fast_tanh(inb[j] + rbuf[j] * hnb[j]);
            float z  = zbuf[j];
            hreg = (1.f - z) * nv + z * hreg;
            hst[j] = hreg;
        }
        __syncthreads();
        gcur = gnext;
    }

    if (j < NCLS) {
        float acc = bc[j];
        #pragma unroll
        for (int h = 0; h < HID; h++) acc += hst[h] * Wc[h * NCLS + j];
        out[b * NCLS + j] = acc;
    }
}

// ---------------------------------------------------------------------------
extern "C" void kernel_launch(void* const* d_in, const int* in_sizes, int n_in,
                              void* d_out, int out_size, void* d_ws, size_t ws_size,
                              hipStream_t stream) {
    const float* x_seq   = (const float*)d_in[0];
    const float* adj_seq = (const float*)d_in[1];
    const float* Wp      = (const float*)d_in[2];
    const float* bp      = (const float*)d_in[3];
    const float* W_ih    = (const float*)d_in[4];
    const float* W_hh    = (const float*)d_in[5];
    const float* b_ih    = (const float*)d_in[6];
    const float* b_hh    = (const float*)d_in[7];
    const float* Wc      = (const float*)d_in[8];
    const float* bc      = (const float*)d_in[9];

    float* gi  = (float*)d_ws;           // B*T*G3 floats = 768 KiB
    float* out = (float*)d_out;

    feats_gi_kernel<<<BB * TT, 512, 0, stream>>>(x_seq, adj_seq, Wp, bp,
                                                 W_ih, b_ih, gi);
    gru_kernel<<<BB, 192, 0, stream>>>(gi, W_hh, b_hh, Wc, bc, out);
}